// Round 6
// baseline (1693.477 us; speedup 1.0000x reference)
//
#include <hip/hip_runtime.h>

// Per-joint 3D Euclidean distance, mean over B*21 joints.
// B = 1048576, NUM_JOINTS = 21 -> 66,060,288 fp32 per input (252 MiB each).
// Streaming-read reduction; floor ~= 528 MB / 6.8 TB/s ~= 78 us.
//
// R9: CORRECTED DIAGNOSTIC (R8's BLOCKS=512 failed to surface the kernel:
// 2048 waves x ~6KB in-flight = 12 MB >> 2.5 MB BW*latency product, so it
// stayed HBM-saturated and hidden under the ~159 us harness fills; total
// moved -3.7 us = noise across a 3.5x occupancy cut => kernel is BW-bound,
// not latency/issue-bound).
// History: R1/R2/R3 ~= 492-500; R4 (coalesced+nt+bpermute) = 467.7;
// R7 (no atomics, exact balance, BLOCKS=1792) = 465.1; R8 (BLOCKS=512) =
// 461.4. Unknowns: actual kernel time (85 vs 140 us) and FETCH_SIZE
// (over-fetch?). Both require the kernel to SURFACE in top-5.
// Fix: BLOCKS=16 -> 64 waves, ~384-768 KB in flight -> ~1-2 TB/s ->
// kernel ~260-530 us -> guaranteed top-1 with its own counter row.
// 86016 / 64 waves = 1344.0 exact (balance preserved). Body byte-identical.
// Readouts: (1) FETCH_SIZE vs 516,100 KB line-exact ideal;
// (2) kernel_1792 = kernel_16 - (total_16 - total_1792).
// Next round reverts to BLOCKS=1792 regardless.

#define TPB 256
#define BLOCKS 16    // DIAGNOSTIC: 64 waves; 86016/64 = 1344 chunks exact

typedef float f32x4 __attribute__((ext_vector_type(4)));

// USE_WS=1: write per-block partial to partials[blockIdx.x] (no atomics).
// USE_WS=0: atomicAdd(out, bsum * inv_count)  (R4 behavior).
template <int USE_WS>
__global__ __launch_bounds__(TPB) void joint_dist_kernel(
    const float* __restrict__ pred,
    const float* __restrict__ target,
    float* __restrict__ sink,   // partials (USE_WS) or out (atomic path)
    int nchunks,                // number of 768-float chunks (exactly divisible)
    float inv_count)
{
    const f32x4* __restrict__ p4 = (const f32x4*)pred;
    const f32x4* __restrict__ t4 = (const f32x4*)target;

    const int lane   = threadIdx.x & 63;
    const int wave   = (blockIdx.x * TPB + threadIdx.x) >> 6;
    const int nwaves = (gridDim.x * TPB) >> 6;

    // Per-lane-constant redistribution pattern (hoisted out of the loop):
    // lane needs s-vectors u = 3*lane + j of its wave's 192-vector chunk.
    int addr0, addr1, addr2;   // ds_bpermute byte addr = (u & 63) * 4
    int r0, r1, r2;            // which phase register holds u: u >> 6
    {
        int u0 = 3 * lane + 0, u1 = 3 * lane + 1, u2 = 3 * lane + 2;
        addr0 = (u0 & 63) << 2; r0 = u0 >> 6;
        addr1 = (u1 & 63) << 2; r1 = u1 >> 6;
        addr2 = (u2 & 63) << 2; r2 = u2 >> 6;
    }

    float acc = 0.0f;
    for (int c = wave; c < nchunks; c += nwaves) {
        const int base = c * 192 + lane;
        // Coalesced: lane stride 16 B, each 64 B line read once by one instr.
        // nt: line-exact streaming, no L2/L3 allocation or victim evictions.
        f32x4 pa0 = __builtin_nontemporal_load(&p4[base]);
        f32x4 pa1 = __builtin_nontemporal_load(&p4[base + 64]);
        f32x4 pa2 = __builtin_nontemporal_load(&p4[base + 128]);
        f32x4 tb0 = __builtin_nontemporal_load(&t4[base]);
        f32x4 tb1 = __builtin_nontemporal_load(&t4[base + 64]);
        f32x4 tb2 = __builtin_nontemporal_load(&t4[base + 128]);

        // Componentwise: indices of p and t align, no cross-lane needed yet.
        f32x4 d0 = pa0 - tb0, d1 = pa1 - tb1, d2 = pa2 - tb2;
        f32x4 s0 = d0 * d0,   s1 = d1 * d1,   s2 = d2 * d2;

        // Redistribute ONLY the squares: lane pulls s-vectors 3l, 3l+1, 3l+2.
        float o[12];
        #pragma unroll
        for (int k = 0; k < 4; ++k) {
            {
                int x0 = __builtin_amdgcn_ds_bpermute(addr0, __float_as_int(s0[k]));
                int x1 = __builtin_amdgcn_ds_bpermute(addr0, __float_as_int(s1[k]));
                int x2 = __builtin_amdgcn_ds_bpermute(addr0, __float_as_int(s2[k]));
                o[0 * 4 + k] = __int_as_float(r0 == 0 ? x0 : (r0 == 1 ? x1 : x2));
            }
            {
                int x0 = __builtin_amdgcn_ds_bpermute(addr1, __float_as_int(s0[k]));
                int x1 = __builtin_amdgcn_ds_bpermute(addr1, __float_as_int(s1[k]));
                int x2 = __builtin_amdgcn_ds_bpermute(addr1, __float_as_int(s2[k]));
                o[1 * 4 + k] = __int_as_float(r1 == 0 ? x0 : (r1 == 1 ? x1 : x2));
            }
            {
                int x0 = __builtin_amdgcn_ds_bpermute(addr2, __float_as_int(s0[k]));
                int x1 = __builtin_amdgcn_ds_bpermute(addr2, __float_as_int(s1[k]));
                int x2 = __builtin_amdgcn_ds_bpermute(addr2, __float_as_int(s2[k]));
                o[2 * 4 + k] = __int_as_float(r2 == 0 ? x0 : (r2 == 1 ? x1 : x2));
            }
        }

        // Lane-local floats [12l, 12l+12) = joints 4l..4l+3.
        acc += sqrtf(o[0] + o[1]  + o[2]);
        acc += sqrtf(o[3] + o[4]  + o[5]);
        acc += sqrtf(o[6] + o[7]  + o[8]);
        acc += sqrtf(o[9] + o[10] + o[11]);
    }

    // 64-lane wave reduction
    #pragma unroll
    for (int off = 32; off > 0; off >>= 1)
        acc += __shfl_down(acc, off, 64);

    __shared__ float wsum[TPB / 64];
    int wid = threadIdx.x >> 6;
    if (lane == 0) wsum[wid] = acc;
    __syncthreads();

    if (threadIdx.x == 0) {
        float bsum = wsum[0] + wsum[1] + wsum[2] + wsum[3];
        if (USE_WS) {
            // Plain store to a private slot: ZERO atomics, no cross-XCD
            // same-address serialization.
            sink[blockIdx.x] = bsum;
        } else {
            // Fallback (R4): d_out poison 0xAAAAAAAA == -3.03e-13f absorbed.
            atomicAdd(sink, bsum * inv_count);
        }
    }
}

__global__ __launch_bounds__(TPB) void reduce_kernel(
    const float* __restrict__ partials,
    float* __restrict__ out,
    float inv_count)
{
    float acc = 0.0f;
    for (int i = threadIdx.x; i < BLOCKS; i += TPB)
        acc += partials[i];

    #pragma unroll
    for (int off = 32; off > 0; off >>= 1)
        acc += __shfl_down(acc, off, 64);

    __shared__ float wsum[TPB / 64];
    int lane = threadIdx.x & 63;
    int wid  = threadIdx.x >> 6;
    if (lane == 0) wsum[wid] = acc;
    __syncthreads();

    if (threadIdx.x == 0) {
        // Plain store (overwrites d_out poison exactly).
        out[0] = (wsum[0] + wsum[1] + wsum[2] + wsum[3]) * inv_count;
    }
}

extern "C" void kernel_launch(void* const* d_in, const int* in_sizes, int n_in,
                              void* d_out, int out_size, void* d_ws, size_t ws_size,
                              hipStream_t stream) {
    const float* pred   = (const float*)d_in[0];
    const float* target = (const float*)d_in[1];
    float* out      = (float*)d_out;
    float* partials = (float*)d_ws;   // BLOCKS * 4 B

    int total_floats = in_sizes[0];         // 66,060,288
    int nchunks      = total_floats / 768;  // 86,016 (exact)
    int njoints      = total_floats / 3;    // 22,020,096
    float inv_count  = 1.0f / (float)njoints;

    if (d_ws != nullptr && ws_size >= BLOCKS * sizeof(float)) {
        joint_dist_kernel<1><<<BLOCKS, TPB, 0, stream>>>(pred, target, partials,
                                                         nchunks, inv_count);
        reduce_kernel<<<1, TPB, 0, stream>>>(partials, out, inv_count);
    } else {
        // Fallback: proven R4 single-kernel atomic path (no workspace use).
        joint_dist_kernel<0><<<BLOCKS, TPB, 0, stream>>>(pred, target, out,
                                                         nchunks, inv_count);
    }
}

// Round 7
// 463.562 us; speedup vs baseline: 3.6532x; 3.6532x over previous
//
#include <hip/hip_runtime.h>

// Per-joint 3D Euclidean distance, mean over B*21 joints.
// B = 1048576, NUM_JOINTS = 21 -> 66,060,288 fp32 per input (252 MiB each).
//
// R10: revert R9 diagnostic -> production config (== R7, BLOCKS=1792).
// FINAL ANALYSIS (from R9's direct observation, BLOCKS=16 probe):
//   kernel FETCH_SIZE = 258,072 KB = exactly half of the logical 528 MB:
//   ~50% of reads hit Infinity Cache (restore pass leaves ~256 MiB of the
//   504 MiB input set L3-resident; nt = no-allocate but hits still hit).
//   No over-fetch. kernel_1792 = 1315.9 - (1693.5 - 465.1) = 87.6 us
//   => 528 MB / 87.6 us = 6.03 TB/s effective = ~96% of the measured
//   achievable streaming ceiling (6.29 TB/s float4-copy ubench), i.e.
//   ~9.8 B/cyc/CU at the ~10 B/cyc/CU request-path ceiling. VALU ~12%
//   at full grid. Remaining kernel headroom <= 4 us < total noise (+-8).
//   The other ~377 us of the 465 us total is harness fill/restore traffic
//   itself running at 83-85% of HBM peak. ROOFLINE.
// History: R1/R2/R3 (strided/LDS/strided+nt) ~= 492-500;
//   R4 (coalesced+nt+bpermute, atomics) = 467.7;
//   R7 (partials in d_ws, 1792 blocks, 12.0 chunks/wave exact) = 465.1;
//   R8 (512 blocks) = 461.4 (same within noise);
//   R9 (16-block diagnostic) = 1693.5 (deliberate).

#define TPB 256
#define BLOCKS 1792  // 7 blocks/CU; 86016 wave-chunks / 7168 waves = 12 exact

typedef float f32x4 __attribute__((ext_vector_type(4)));

// USE_WS=1: write per-block partial to partials[blockIdx.x] (no atomics).
// USE_WS=0: atomicAdd(out, bsum * inv_count)  (R4 behavior, fallback).
template <int USE_WS>
__global__ __launch_bounds__(TPB) void joint_dist_kernel(
    const float* __restrict__ pred,
    const float* __restrict__ target,
    float* __restrict__ sink,   // partials (USE_WS) or out (atomic path)
    int nchunks,                // number of 768-float chunks (exactly divisible)
    float inv_count)
{
    const f32x4* __restrict__ p4 = (const f32x4*)pred;
    const f32x4* __restrict__ t4 = (const f32x4*)target;

    const int lane   = threadIdx.x & 63;
    const int wave   = (blockIdx.x * TPB + threadIdx.x) >> 6;
    const int nwaves = (gridDim.x * TPB) >> 6;

    // Per-lane-constant redistribution pattern (hoisted out of the loop):
    // lane needs s-vectors u = 3*lane + j of its wave's 192-vector chunk.
    int addr0, addr1, addr2;   // ds_bpermute byte addr = (u & 63) * 4
    int r0, r1, r2;            // which phase register holds u: u >> 6
    {
        int u0 = 3 * lane + 0, u1 = 3 * lane + 1, u2 = 3 * lane + 2;
        addr0 = (u0 & 63) << 2; r0 = u0 >> 6;
        addr1 = (u1 & 63) << 2; r1 = u1 >> 6;
        addr2 = (u2 & 63) << 2; r2 = u2 >> 6;
    }

    float acc = 0.0f;
    for (int c = wave; c < nchunks; c += nwaves) {
        const int base = c * 192 + lane;
        // Coalesced: lane stride 16 B, each 64 B line read once by one instr.
        // nt: line-exact streaming, no L2/L3 allocation or victim evictions.
        f32x4 pa0 = __builtin_nontemporal_load(&p4[base]);
        f32x4 pa1 = __builtin_nontemporal_load(&p4[base + 64]);
        f32x4 pa2 = __builtin_nontemporal_load(&p4[base + 128]);
        f32x4 tb0 = __builtin_nontemporal_load(&t4[base]);
        f32x4 tb1 = __builtin_nontemporal_load(&t4[base + 64]);
        f32x4 tb2 = __builtin_nontemporal_load(&t4[base + 128]);

        // Componentwise: indices of p and t align, no cross-lane needed yet.
        f32x4 d0 = pa0 - tb0, d1 = pa1 - tb1, d2 = pa2 - tb2;
        f32x4 s0 = d0 * d0,   s1 = d1 * d1,   s2 = d2 * d2;

        // Redistribute ONLY the squares: lane pulls s-vectors 3l, 3l+1, 3l+2.
        float o[12];
        #pragma unroll
        for (int k = 0; k < 4; ++k) {
            {
                int x0 = __builtin_amdgcn_ds_bpermute(addr0, __float_as_int(s0[k]));
                int x1 = __builtin_amdgcn_ds_bpermute(addr0, __float_as_int(s1[k]));
                int x2 = __builtin_amdgcn_ds_bpermute(addr0, __float_as_int(s2[k]));
                o[0 * 4 + k] = __int_as_float(r0 == 0 ? x0 : (r0 == 1 ? x1 : x2));
            }
            {
                int x0 = __builtin_amdgcn_ds_bpermute(addr1, __float_as_int(s0[k]));
                int x1 = __builtin_amdgcn_ds_bpermute(addr1, __float_as_int(s1[k]));
                int x2 = __builtin_amdgcn_ds_bpermute(addr1, __float_as_int(s2[k]));
                o[1 * 4 + k] = __int_as_float(r1 == 0 ? x0 : (r1 == 1 ? x1 : x2));
            }
            {
                int x0 = __builtin_amdgcn_ds_bpermute(addr2, __float_as_int(s0[k]));
                int x1 = __builtin_amdgcn_ds_bpermute(addr2, __float_as_int(s1[k]));
                int x2 = __builtin_amdgcn_ds_bpermute(addr2, __float_as_int(s2[k]));
                o[2 * 4 + k] = __int_as_float(r2 == 0 ? x0 : (r2 == 1 ? x1 : x2));
            }
        }

        // Lane-local floats [12l, 12l+12) = joints 4l..4l+3.
        acc += sqrtf(o[0] + o[1]  + o[2]);
        acc += sqrtf(o[3] + o[4]  + o[5]);
        acc += sqrtf(o[6] + o[7]  + o[8]);
        acc += sqrtf(o[9] + o[10] + o[11]);
    }

    // 64-lane wave reduction
    #pragma unroll
    for (int off = 32; off > 0; off >>= 1)
        acc += __shfl_down(acc, off, 64);

    __shared__ float wsum[TPB / 64];
    int wid = threadIdx.x >> 6;
    if (lane == 0) wsum[wid] = acc;
    __syncthreads();

    if (threadIdx.x == 0) {
        float bsum = wsum[0] + wsum[1] + wsum[2] + wsum[3];
        if (USE_WS) {
            // Plain store to a private slot: ZERO atomics, no cross-XCD
            // same-address serialization.
            sink[blockIdx.x] = bsum;
        } else {
            // Fallback (R4): d_out poison 0xAAAAAAAA == -3.03e-13f absorbed.
            atomicAdd(sink, bsum * inv_count);
        }
    }
}

__global__ __launch_bounds__(TPB) void reduce_kernel(
    const float* __restrict__ partials,
    float* __restrict__ out,
    float inv_count)
{
    float acc = 0.0f;
    for (int i = threadIdx.x; i < BLOCKS; i += TPB)
        acc += partials[i];

    #pragma unroll
    for (int off = 32; off > 0; off >>= 1)
        acc += __shfl_down(acc, off, 64);

    __shared__ float wsum[TPB / 64];
    int lane = threadIdx.x & 63;
    int wid  = threadIdx.x >> 6;
    if (lane == 0) wsum[wid] = acc;
    __syncthreads();

    if (threadIdx.x == 0) {
        // Plain store (overwrites d_out poison exactly).
        out[0] = (wsum[0] + wsum[1] + wsum[2] + wsum[3]) * inv_count;
    }
}

extern "C" void kernel_launch(void* const* d_in, const int* in_sizes, int n_in,
                              void* d_out, int out_size, void* d_ws, size_t ws_size,
                              hipStream_t stream) {
    const float* pred   = (const float*)d_in[0];
    const float* target = (const float*)d_in[1];
    float* out      = (float*)d_out;
    float* partials = (float*)d_ws;   // BLOCKS * 4 B = 7 KiB

    int total_floats = in_sizes[0];         // 66,060,288
    int nchunks      = total_floats / 768;  // 86,016 (exact)
    int njoints      = total_floats / 3;    // 22,020,096
    float inv_count  = 1.0f / (float)njoints;

    if (d_ws != nullptr && ws_size >= BLOCKS * sizeof(float)) {
        joint_dist_kernel<1><<<BLOCKS, TPB, 0, stream>>>(pred, target, partials,
                                                         nchunks, inv_count);
        reduce_kernel<<<1, TPB, 0, stream>>>(partials, out, inv_count);
    } else {
        // Fallback: proven R4 single-kernel atomic path (no workspace use).
        joint_dist_kernel<0><<<BLOCKS, TPB, 0, stream>>>(pred, target, out,
                                                         nchunks, inv_count);
    }
}